// Round 4
// baseline (1625.173 us; speedup 1.0000x reference)
//
#include <hip/hip_runtime.h>
#include <hip/hip_bf16.h>

#define SLEN 1024
#define BSZ 32
#define NHEAD 16
#define DHEAD 64
#define INDIM 1024

typedef __attribute__((ext_vector_type(8))) __bf16 bf16x8;
typedef __attribute__((ext_vector_type(4))) float f32x4;
typedef __attribute__((ext_vector_type(2))) float f32x2;

#if __has_builtin(__builtin_elementwise_fma)
__device__ __forceinline__ f32x2 pk_fma(f32x2 a, f32x2 b, f32x2 c) {
  return __builtin_elementwise_fma(a, b, c);
}
#else
__device__ __forceinline__ f32x2 pk_fma(f32x2 a, f32x2 b, f32x2 c) {
  f32x2 r; r.x = fmaf(a.x, b.x, c.x); r.y = fmaf(a.y, b.y, c.y); return r;
}
#endif

// ---------------------------------------------------------------------------
// DPP-based wave-64 reductions (pure VALU, 6 dependent stages).
// ---------------------------------------------------------------------------
template <int C>
__device__ __forceinline__ float dppmov(float v) {
  return __int_as_float(__builtin_amdgcn_update_dpp(
      __float_as_int(v), __float_as_int(v), C, 0xF, 0xF, false));
}
__device__ __forceinline__ float wred_sum_u(float v) {
  v += dppmov<0x111>(v);   // row_shr:1
  v += dppmov<0x112>(v);   // row_shr:2
  v += dppmov<0x114>(v);   // row_shr:4
  v += dppmov<0x118>(v);   // row_shr:8
  v += dppmov<0x142>(v);   // row_bcast:15
  v += dppmov<0x143>(v);   // row_bcast:31
  return __int_as_float(__builtin_amdgcn_readlane(__float_as_int(v), 63));
}
__device__ __forceinline__ float wred_max_u(float v) {
  v = fmaxf(v, dppmov<0x111>(v));
  v = fmaxf(v, dppmov<0x112>(v));
  v = fmaxf(v, dppmov<0x114>(v));
  v = fmaxf(v, dppmov<0x118>(v));
  v = fmaxf(v, dppmov<0x142>(v));
  v = fmaxf(v, dppmov<0x143>(v));
  return __int_as_float(__builtin_amdgcn_readlane(__float_as_int(v), 63));
}

// ---------------------------------------------------------------------------
// Scan kernel: one (b,head) pair per 256-thread block (4 waves).
// waves 0-2: lane l owns row l of Wy/Wq/Wk as 32 f32x2 (packed-fp32 math)
// wave 3: lane d owns wb[d][0..3]; computes beta; manages x double-buffer
//
// Deferred rank-1 materialization: phase B only computes sc and keeps k in
// registers; phase A(t+1) computes the dot on the stale W, adds the exact
// correction sc_pend*(k_pend . x) (one DPP-reduced scalar), and materializes
// W += sc_pend (x) k_pend in the softmax/barrier shadow. All global memory
// ops (x load, batched y store) are issued in the POST-barrier region so the
// compiler's vmcnt(0)-before-barrier drain does not serialize their latency.
// ---------------------------------------------------------------------------
__global__ __launch_bounds__(256, 2) void srwm_scan(
    const float* __restrict__ h,
    const float* __restrict__ Wy0, const float* __restrict__ Wq0,
    const float* __restrict__ Wk0, const float* __restrict__ wb0,
    __hip_bfloat16* __restrict__ ys)
{
  const int p  = blockIdx.x;          // 0..511
  const int b  = p >> 4;
  const int hd = p & 15;
  const int tid = threadIdx.x;
  const int w = tid >> 6, l = tid & 63;

  __shared__ float sx[2][64];
  __shared__ float sq[2][64];
  __shared__ float sk[2][64];
  __shared__ float sbeta[2][4];
  __shared__ __hip_bfloat16 ysbuf[8][64];   // wave-0 private y staging

  f32x2 wrow[32];   // waves 0-2: full W row; wave 3: [0..1] = wb row (4 vals)
  f32x2 kr[32];     // register-carried k_pend (written B(t), used A(t+1))
  float sc_pend = 0.f;
  float xnext = 0.f;
  float cshift = 0.f;   // deferred softmax shift (wave-uniform)

  if (w < 3) {
    const float* base = (w == 0) ? Wy0 : (w == 1) ? Wq0 : Wk0;
    const float4* s4 = (const float4*)(base + (size_t)(hd * DHEAD + l) * DHEAD);
#pragma unroll
    for (int c = 0; c < 16; ++c) {
      const float4 v = s4[c];
      wrow[2 * c + 0] = f32x2{v.x, v.y};
      wrow[2 * c + 1] = f32x2{v.z, v.w};
    }
#pragma unroll
    for (int c = 0; c < 32; ++c) kr[c] = (f32x2)(0.f);
    if (w == 2) sk[1][l] = 0.f;     // read (x0) by A(0)'s correction
  } else {
    const float4 v = *(const float4*)(wb0 + (size_t)(hd * DHEAD + l) * 4);
    wrow[0] = f32x2{v.x, v.y};
    wrow[1] = f32x2{v.z, v.w};
    // x_0 into buffer 0, x_1 prefetched into xnext
    sx[0][l] = h[(size_t)b * INDIM + hd * DHEAD + l];
    xnext = h[(size_t)BSZ * INDIM + (size_t)b * INDIM + hd * DHEAD + l];
  }
  __syncthreads();

  const size_t xstride = (size_t)BSZ * INDIM;
  const float* xsrc = h + (size_t)b * INDIM + hd * DHEAD + l;
  __hip_bfloat16* ybase = ys + (size_t)b * INDIM + hd * DHEAD;

#pragma unroll 2
  for (int t = 0; t < SLEN; ++t) {
    const int cur = t & 1, nxt = cur ^ 1, prev = nxt;
    // ---------------- Phase A ----------------
    if (w < 3) {
      const float* xb = sx[cur];
      // dot on stale W (4 independent chains)
      f32x2 a0 = (f32x2)(0.f), a1 = (f32x2)(0.f);
      f32x2 a2 = (f32x2)(0.f), a3 = (f32x2)(0.f);
#pragma unroll
      for (int c = 0; c < 8; ++c) {
        const float4 x0 = *(const float4*)(xb + 8 * c);
        const float4 x1 = *(const float4*)(xb + 8 * c + 4);
        a0 = pk_fma(wrow[4 * c + 0], f32x2{x0.x, x0.y}, a0);
        a1 = pk_fma(wrow[4 * c + 1], f32x2{x0.z, x0.w}, a1);
        a2 = pk_fma(wrow[4 * c + 2], f32x2{x1.x, x1.y}, a2);
        a3 = pk_fma(wrow[4 * c + 3], f32x2{x1.z, x1.w}, a3);
      }
      const f32x2 as = (a0 + a1) + (a2 + a3);
      // exact correction for the pending rank-1 update (off the FMA chain)
      const float rl = sk[prev][l] * xb[l];
      const float r  = wred_sum_u(rl);
      const float a  = (as.x + as.y) + sc_pend * r;
      // deferred-shift softmax: max chain off the critical path
      const float e = __expf(a - cshift);
      const float mnew = wred_max_u(a);
      const float s = wred_sum_u(e);
      const float sm = e * __builtin_amdgcn_rcpf(s);
      cshift = mnew;
      if (w == 0) {
        ysbuf[t & 7][l] = __float2bfloat16(sm);
      } else if (w == 1) {
        sq[cur][l] = sm;
      } else {
        sk[cur][l] = sm;
      }
      // materialize pending update in the softmax/barrier shadow
      const f32x2 spv = (f32x2)(sc_pend);
#pragma unroll
      for (int c = 0; c < 32; ++c) wrow[c] = pk_fma(spv, kr[c], wrow[c]);
    } else {
      // publish x_{t+1} (register-carried since B(t-1))
      sx[nxt][l] = xnext;
      // beta = sigmoid(wb^T x_t): 4 independent DPP reduction chains
      const float xd = sx[cur][l];
      const float z0 = wred_sum_u(wrow[0].x * xd);
      const float z1 = wred_sum_u(wrow[0].y * xd);
      const float z2 = wred_sum_u(wrow[1].x * xd);
      const float z3 = wred_sum_u(wrow[1].y * xd);
      if (l == 0) {
        sbeta[cur][0] = __builtin_amdgcn_rcpf(1.f + __expf(-z0));
        sbeta[cur][1] = __builtin_amdgcn_rcpf(1.f + __expf(-z1));
        sbeta[cur][2] = __builtin_amdgcn_rcpf(1.f + __expf(-z2));
        sbeta[cur][3] = __builtin_amdgcn_rcpf(1.f + __expf(-z3));
      }
    }
    __syncthreads();   // the only barrier per step
    // ---------------- Phase B (post-barrier: all global ops live here) -----
    if (w < 3) {
      if (w == 0 && (t & 7) == 7) {
        // batched y flush: 8 steps x 64 lanes, 1 KiB coalesced
        const uint4 v = ((const uint4*)ysbuf)[l];
        const int t0 = t - 7 + (l >> 3);
        *(uint4*)(ybase + (size_t)t0 * xstride + (l & 7) * 8) = v;
      }
      const float* qb = sq[cur];
      const float* kb = sk[cur];
      const float beta = sbeta[cur][w];
      f32x2 d0 = (f32x2)(0.f), d1 = (f32x2)(0.f);
      f32x2 d2 = (f32x2)(0.f), d3 = (f32x2)(0.f);
#pragma unroll
      for (int c = 0; c < 8; ++c) {
        const float4 q0 = *(const float4*)(qb + 8 * c);
        const float4 q1 = *(const float4*)(qb + 8 * c + 4);
        const float4 k0 = *(const float4*)(kb + 8 * c);
        const float4 k1 = *(const float4*)(kb + 8 * c + 4);
        const f32x2 ka = f32x2{k0.x, k0.y}, kb2 = f32x2{k0.z, k0.w};
        const f32x2 kc = f32x2{k1.x, k1.y}, kd = f32x2{k1.z, k1.w};
        kr[4 * c + 0] = ka; kr[4 * c + 1] = kb2;
        kr[4 * c + 2] = kc; kr[4 * c + 3] = kd;
        d0 = pk_fma(wrow[4 * c + 0], f32x2{q0.x, q0.y} - ka,  d0);
        d1 = pk_fma(wrow[4 * c + 1], f32x2{q0.z, q0.w} - kb2, d1);
        d2 = pk_fma(wrow[4 * c + 2], f32x2{q1.x, q1.y} - kc,  d2);
        d3 = pk_fma(wrow[4 * c + 3], f32x2{q1.z, q1.w} - kd,  d3);
      }
      const f32x2 ds = (d0 + d1) + (d2 + d3);
      sc_pend = beta * (ds.x + ds.y);   // W update deferred to A(t+1)
    } else {
      // issue x(t+2) load AFTER the barrier: a full phase before its drain
      const int tload = (t + 2 < SLEN) ? (t + 2) : (SLEN - 1);
      xnext = xsrc[(size_t)tload * xstride];
      // wb update (immediate): wb[l][j] += beta3 * k_l * (wb^T(q-k))_j
      const float qd = sq[cur][l], kd = sk[cur][l];
      const float dd = qd - kd;
      const float z0 = wred_sum_u(wrow[0].x * dd);
      const float z1 = wred_sum_u(wrow[0].y * dd);
      const float z2 = wred_sum_u(wrow[1].x * dd);
      const float z3 = wred_sum_u(wrow[1].y * dd);
      const float s3 = sbeta[cur][3] * kd;
      wrow[0].x = fmaf(s3, z0, wrow[0].x);
      wrow[0].y = fmaf(s3, z1, wrow[0].y);
      wrow[1].x = fmaf(s3, z2, wrow[1].x);
      wrow[1].y = fmaf(s3, z3, wrow[1].y);
    }
  }
}

// ---------------------------------------------------------------------------
// LayerNorm row stats: mu, rsqrt(var+eps) per (t,b) row of h
// ---------------------------------------------------------------------------
__global__ __launch_bounds__(256) void ln_stats(
    const float* __restrict__ h, float2* __restrict__ stats)
{
  const int row = blockIdx.x * 4 + (threadIdx.x >> 6);
  const int l = threadIdx.x & 63;
  const float4* hp = (const float4*)(h + (size_t)row * INDIM);
  float s = 0.f, s2 = 0.f;
#pragma unroll
  for (int c = 0; c < 4; ++c) {
    const float4 v = hp[c * 64 + l];
    s  += v.x + v.y + v.z + v.w;
    s2 += v.x * v.x + v.y * v.y + v.z * v.z + v.w * v.w;
  }
  s  = wred_sum_u(s);
  s2 = wred_sum_u(s2);
  if (l == 0) {
    const float mu  = s * (1.f / INDIM);
    const float var = s2 * (1.f / INDIM) - mu * mu;
    stats[row] = make_float2(mu, rsqrtf(var + 1e-5f));
  }
}

// ---------------------------------------------------------------------------
// out_w fp32 -> bf16
// ---------------------------------------------------------------------------
__global__ void cvt_bf16(const float* __restrict__ src,
                         __hip_bfloat16* __restrict__ dst, int n)
{
  const int i = blockIdx.x * blockDim.x + threadIdx.x;
  if (i < n) dst[i] = __float2bfloat16(src[i]);
}

// ---------------------------------------------------------------------------
// C[m][n] = sum_k ys[m][k] * W[n][k]  (both K-major), fused LN + residual
// 128x128 tile, BK=32, 4 waves (2x2), each wave 64x64 via 4x4 16x16x32 MFMA
// ---------------------------------------------------------------------------
__global__ __launch_bounds__(256) void gemm_ln(
    const __hip_bfloat16* __restrict__ A,   // ys   (32768,1024)
    const __hip_bfloat16* __restrict__ Bw,  // w    (1024,1024)
    const float* __restrict__ h,
    const float2* __restrict__ stats,
    const float* __restrict__ g,
    const float* __restrict__ bvec,
    float* __restrict__ out)
{
  const int K = INDIM;
  __shared__ __align__(16) __hip_bfloat16 As[128 * 32];
  __shared__ __align__(16) __hip_bfloat16 Bs[128 * 32];
  const int tid = threadIdx.x, w = tid >> 6, l = tid & 63;
  const int wm = w >> 1, wn = w & 1;
  const int m0 = blockIdx.x * 128, n0 = blockIdx.y * 128;

  f32x4 acc[4][4];
#pragma unroll
  for (int i = 0; i < 4; ++i)
#pragma unroll
    for (int j = 0; j < 4; ++j) acc[i][j] = (f32x4)(0.f);

  const int mr = tid >> 2;            // staging row (0..63), pass1 adds 64
  const int kc = (tid & 3) * 8;       // k element offset within 32

  for (int k0 = 0; k0 < K; k0 += 32) {
    const uint4 va0 = *(const uint4*)(A  + (size_t)(m0 + mr)      * K + k0 + kc);
    const uint4 va1 = *(const uint4*)(A  + (size_t)(m0 + mr + 64) * K + k0 + kc);
    const uint4 vb0 = *(const uint4*)(Bw + (size_t)(n0 + mr)      * K + k0 + kc);
    const uint4 vb1 = *(const uint4*)(Bw + (size_t)(n0 + mr + 64) * K + k0 + kc);
    *(uint4*)((char*)As + (size_t)tid * 16)         = va0;
    *(uint4*)((char*)As + (size_t)(tid + 256) * 16) = va1;
    *(uint4*)((char*)Bs + (size_t)tid * 16)         = vb0;
    *(uint4*)((char*)Bs + (size_t)(tid + 256) * 16) = vb1;
    __syncthreads();

    bf16x8 af[4], bfr[4];
    const int koff = (l >> 4) * 16;   // byte offset of this lane's k-group
#pragma unroll
    for (int i = 0; i < 4; ++i) {
      af[i]  = *(const bf16x8*)((const char*)As +
                 (size_t)(wm * 64 + i * 16 + (l & 15)) * 64 + koff);
      bfr[i] = *(const bf16x8*)((const char*)Bs +
                 (size_t)(wn * 64 + i * 16 + (l & 15)) * 64 + koff);
    }
#pragma unroll
    for (int i = 0; i < 4; ++i)
#pragma unroll
      for (int j = 0; j < 4; ++j)
        acc[i][j] = __builtin_amdgcn_mfma_f32_16x16x32_bf16(
            af[i], bfr[j], acc[i][j], 0, 0, 0);
    __syncthreads();
  }

  // epilogue: out = acc + (h - mu)*rsig*g + b
  float gv[4], bv[4];
  int cols[4];
#pragma unroll
  for (int j = 0; j < 4; ++j) {
    const int col = n0 + wn * 64 + j * 16 + (l & 15);
    cols[j] = col; gv[j] = g[col]; bv[j] = bvec[col];
  }
#pragma unroll
  for (int i = 0; i < 4; ++i) {
#pragma unroll
    for (int r = 0; r < 4; ++r) {
      const int row = m0 + wm * 64 + i * 16 + (l >> 4) * 4 + r;
      const float2 st = stats[row];
      const float* hrow = h + (size_t)row * INDIM;
      float* orow = out + (size_t)row * INDIM;
#pragma unroll
      for (int j = 0; j < 4; ++j) {
        const float lnv = (hrow[cols[j]] - st.x) * st.y * gv[j] + bv[j];
        orow[cols[j]] = acc[i][j][r] + lnv;
      }
    }
  }
}

extern "C" void kernel_launch(void* const* d_in, const int* in_sizes, int n_in,
                              void* d_out, int out_size, void* d_ws, size_t ws_size,
                              hipStream_t stream)
{
  const float* h    = (const float*)d_in[0];
  const float* Wy   = (const float*)d_in[1];
  const float* Wq   = (const float*)d_in[2];
  const float* Wk   = (const float*)d_in[3];
  const float* wb   = (const float*)d_in[4];
  const float* outw = (const float*)d_in[5];
  const float* lng  = (const float*)d_in[6];
  const float* lnb  = (const float*)d_in[7];
  float* out = (float*)d_out;

  char* ws = (char*)d_ws;
  __hip_bfloat16* ys  = (__hip_bfloat16*)ws;                       // 67,108,864 B
  __hip_bfloat16* wbf = (__hip_bfloat16*)(ws + 67108864);          //  2,097,152 B
  float2*       stats = (float2*)(ws + 67108864 + 2097152);        //    262,144 B

  cvt_bf16 <<<4096, 256, 0, stream>>>(outw, wbf, INDIM * INDIM);
  ln_stats <<<8192, 256, 0, stream>>>(h, stats);
  srwm_scan<<<512,  256, 0, stream>>>(h, Wy, Wq, Wk, wb, ys);
  gemm_ln  <<<dim3(256, 8), 256, 0, stream>>>(ys, wbf, h, stats, lng, lnb, out);
}